// Round 7
// baseline (420.231 us; speedup 1.0000x reference)
//
#include <hip/hip_runtime.h>

#define T_STEPS 512
#define BATCH   2048
#define IN_F    12
#define E_F     15
#define H_F     20
#define G4      80
#define TC      32
#define NCHUNK  (T_STEPS / TC)

typedef float v2f __attribute__((ext_vector_type(2)));

// LDS float offsets (single wave per block -> no barriers anywhere). 39.6 KB total
// so 4 blocks/CU still fit (160/4 = 40 KB cap).
#define OFF_MD   0                     // [TC][2][12] md chunk                    = 768
#define OFF_HH   768                   // [TC][2][20] h history (stride 20 ok/16B)= 1280
#define OFF_XG   2048                  // [TC][2][20units][4gates]                = 5120
#define OFF_WC   7168                  // 80x12 W_comb                            = 960
#define OFF_BC   8128                  // 80 fused bias                           = 80
#define OFF_WO   8208                  // [3][24] W_out + bias at +72             = 80
#define OFF_WHH  8288                  // 80x20 W_hh linear                       = 1600
#define SMEM_FLOATS 9888               // 39552 bytes

// raw one-time staging aliased into XG area (XG first written in chunk 0's P2)
#define RAW_WEMB (OFF_XG + 0)          // 180
#define RAW_WIH  (OFF_XG + 180)        // 1200
#define RAW_BEMB (OFF_XG + 1380)       // 15
#define RAW_BIH  (OFF_XG + 1395)       // 80
#define RAW_BHH  (OFF_XG + 1475)       // 80

__device__ __forceinline__ float fsig(float x) {
    float e = __builtin_amdgcn_exp2f(x * -1.442695040888963f);
    return __builtin_amdgcn_rcpf(1.0f + e);
}
__device__ __forceinline__ float ftanh(float x) {
    float e = __builtin_amdgcn_exp2f(x * -2.885390081777927f);
    return fmaf(2.0f, __builtin_amdgcn_rcpf(1.0f + e), -1.0f);
}
__device__ __forceinline__ v2f pkfma(v2f a, v2f b, v2f c) {
    return __builtin_elementwise_fma(a, b, c);
}

// Non-rematerializable weight load: volatile asm ds_read must stay where
// written and its result must be carried in VGPRs for its whole live range.
#define LD10(arr, breg) \
    asm volatile("ds_read_b64 %0, %1 offset:0"  : "=v"(arr[0]) : "v"(breg) : "memory"); \
    asm volatile("ds_read_b64 %0, %1 offset:8"  : "=v"(arr[1]) : "v"(breg) : "memory"); \
    asm volatile("ds_read_b64 %0, %1 offset:16" : "=v"(arr[2]) : "v"(breg) : "memory"); \
    asm volatile("ds_read_b64 %0, %1 offset:24" : "=v"(arr[3]) : "v"(breg) : "memory"); \
    asm volatile("ds_read_b64 %0, %1 offset:32" : "=v"(arr[4]) : "v"(breg) : "memory"); \
    asm volatile("ds_read_b64 %0, %1 offset:40" : "=v"(arr[5]) : "v"(breg) : "memory"); \
    asm volatile("ds_read_b64 %0, %1 offset:48" : "=v"(arr[6]) : "v"(breg) : "memory"); \
    asm volatile("ds_read_b64 %0, %1 offset:56" : "=v"(arr[7]) : "v"(breg) : "memory"); \
    asm volatile("ds_read_b64 %0, %1 offset:64" : "=v"(arr[8]) : "v"(breg) : "memory"); \
    asm volatile("ds_read_b64 %0, %1 offset:72" : "=v"(arr[9]) : "v"(breg) : "memory");

__global__ void __launch_bounds__(64)
__attribute__((amdgpu_waves_per_eu(1, 1)))
lstm_tracker_kernel(
    const float* __restrict__ md,
    const float* __restrict__ W_emb, const float* __restrict__ b_emb,
    const float* __restrict__ W_ih,  const float* __restrict__ b_ih,
    const float* __restrict__ W_hh,  const float* __restrict__ b_hh,
    const float* __restrict__ W_out, const float* __restrict__ b_out,
    float* __restrict__ out)
{
    __shared__ __align__(16) float smem[SMEM_FLOATS];
    const int lane = threadIdx.x;          // 0..63
    const int bl   = lane >> 5;            // which of the 2 batch elems
    const int j    = lane & 31;            // hidden unit (active if < 20)
    const int jj   = (j < H_F) ? j : 0;    // clamped for safe addressing
    const size_t bbase = (size_t)blockIdx.x * 2;

    // ---- one-time: stage raw weights ----
    for (int i = lane; i < E_F * IN_F; i += 64) smem[RAW_WEMB + i] = W_emb[i];
    for (int i = lane; i < G4 * E_F;  i += 64) smem[RAW_WIH  + i] = W_ih[i];
    if (lane < E_F) smem[RAW_BEMB + lane] = b_emb[lane];
    for (int g = lane; g < G4; g += 64) smem[RAW_BIH + g] = b_ih[g];
    for (int g = lane; g < G4; g += 64) smem[RAW_BHH + g] = b_hh[g];
    // W_out rows (padded 24) + bias at +72
    for (int i = lane; i < 3 * H_F; i += 64) {
        int r = i / H_F, k = i - r * H_F;
        smem[OFF_WO + r * 24 + k] = W_out[i];
    }
    if (lane < 3) smem[OFF_WO + 72 + lane] = b_out[lane];
    // W_hh linear into LDS
    for (int i = lane; i < G4 * H_F; i += 64) smem[OFF_WHH + i] = W_hh[i];

    // ---- one-time: W_comb = W_ih @ W_emb (80x12); b_comb = W_ih@b_emb + b_ih + b_hh ----
    for (int idx = lane; idx < G4 * IN_F; idx += 64) {
        int g = idx / IN_F, c = idx - g * IN_F;
        float s = 0.f;
        #pragma unroll
        for (int e = 0; e < E_F; ++e)
            s += smem[RAW_WIH + g * E_F + e] * smem[RAW_WEMB + e * IN_F + c];
        smem[OFF_WC + idx] = s;
    }
    for (int g = lane; g < G4; g += 64) {
        float s = smem[RAW_BIH + g] + smem[RAW_BHH + g];
        #pragma unroll
        for (int e = 0; e < E_F; ++e)
            s += smem[RAW_WIH + g * E_F + e] * smem[RAW_BEMB + e];
        smem[OFF_BC + g] = s;
    }

    // ---- W_hh -> registers via volatile asm (non-remat, carried 512 steps) ----
    v2f whI[10], whF[10], whG[10], whO[10];
    {
        const int bI = OFF_WHH * 4 + jj * 80;          // row jj       (gate i)
        const int bF = bI + 1600;                      // row jj + 20  (gate f)
        const int bG = bI + 3200;                      // row jj + 40  (gate g)
        const int bO = bI + 4800;                      // row jj + 60  (gate o)
        LD10(whI, bI); LD10(whF, bF); LD10(whG, bG); LD10(whO, bO);
        asm volatile("s_waitcnt lgkmcnt(0)" ::: "memory");
        __builtin_amdgcn_sched_barrier(0);
    }

    v2f h2[10];
    #pragma unroll
    for (int k = 0; k < 10; ++k) h2[k] = (v2f){0.f, 0.f};
    float cc = 0.f;

    #pragma unroll 1
    for (int ch = 0; ch < NCHUNK; ++ch) {
        // ---- P0: stage md chunk (coalesced 96B/row) ----
        for (int idx = lane; idx < TC * 6; idx += 64) {
            int tt = idx / 6, w = idx - tt * 6;
            const float* src = md + ((size_t)(ch * TC + tt) * BATCH + bbase) * IN_F + w * 4;
            *(float4*)(smem + OFF_MD + tt * 24 + w * 4) = *(const float4*)src;
        }

        // ---- P2: x_gates for chunk, interleaved [tt][bb][unit][gate] ----
        for (int base = 0; base < TC * 160; base += 64) {
            int idx = base + lane;
            int tt = idx / 160, r = idx - tt * 160;
            int bb = (r >= G4) ? 1 : 0;
            int gi = r - bb * G4;                 // 0..79 = weight row (i,f,g,o blocks)
            int sel = gi / H_F, ju = gi - sel * H_F;
            const float4* m4 = (const float4*)(smem + OFF_MD + tt * 24 + bb * IN_F);
            const float4* w4 = (const float4*)(smem + OFF_WC + gi * IN_F);
            float4 m0 = m4[0], m1 = m4[1], m2 = m4[2];
            float4 q0 = w4[0], q1 = w4[1], q2 = w4[2];
            float s = smem[OFF_BC + gi];
            s += m0.x*q0.x + m0.y*q0.y + m0.z*q0.z + m0.w*q0.w
               + m1.x*q1.x + m1.y*q1.y + m1.z*q1.z + m1.w*q1.w
               + m2.x*q2.x + m2.y*q2.y + m2.z*q2.z + m2.w*q2.w;
            smem[OFF_XG + (tt * 2 + bb) * G4 + ju * 4 + sel] = s;
        }

        // ---- P3: TC recurrent steps ----
        float4 xv = *(const float4*)(smem + OFF_XG + bl * G4 + jj * 4);
        #pragma unroll 1
        for (int tt = 0; tt < TC; ++tt) {
            // prefetch next step's gate inputs (independent of h)
            const int tn = (tt + 1 < TC) ? tt + 1 : tt;
            float4 xnext = *(const float4*)(smem + OFF_XG + (tn * 2 + bl) * G4 + jj * 4);

            // recurrent dots seeded with x-gate inputs
            v2f aI = {xv.x, 0.f}, aF = {xv.y, 0.f}, aG = {xv.z, 0.f}, aO = {xv.w, 0.f};
            #pragma unroll
            for (int k = 0; k < 10; ++k) {
                aI = pkfma(whI[k], h2[k], aI);
                aF = pkfma(whF[k], h2[k], aF);
                aG = pkfma(whG[k], h2[k], aG);
                aO = pkfma(whO[k], h2[k], aO);
            }
            float ai = aI.x + aI.y;
            float af = aF.x + aF.y;
            float ag = aG.x + aG.y;
            float ao = aO.x + aO.y;

            float gi = fsig(ai);
            float gf = fsig(af);
            float gt = ftanh(ag);
            float go = fsig(ao);
            cc = fmaf(gf, cc, gi * gt);
            float hown = go * ftanh(cc);

            // h -> history slot (P4 consumes), then broadcast read (1 LDS RT)
            float* hslot = smem + OFF_HH + tt * 40 + bl * 20;
            if (j < H_F) hslot[j] = hown;
            const float4* hr = (const float4*)hslot;
            float4 h0 = hr[0], h1 = hr[1], hx = hr[2], h3 = hr[3], h4 = hr[4];
            h2[0] = (v2f){h0.x, h0.y}; h2[1] = (v2f){h0.z, h0.w};
            h2[2] = (v2f){h1.x, h1.y}; h2[3] = (v2f){h1.z, h1.w};
            h2[4] = (v2f){hx.x, hx.y}; h2[5] = (v2f){hx.z, hx.w};
            h2[6] = (v2f){h3.x, h3.y}; h2[7] = (v2f){h3.z, h3.w};
            h2[8] = (v2f){h4.x, h4.y}; h2[9] = (v2f){h4.z, h4.w};

            xv = xnext;
        }

        // ---- P4: chunk projection + store ----
        for (int idx = lane; idx < TC * 6; idx += 64) {
            int tt = idx / 6, rem = idx - tt * 6;
            int bb = rem / 3, r = rem - bb * 3;
            const float4* hp = (const float4*)(smem + OFF_HH + tt * 40 + bb * 20);
            const float4* wp = (const float4*)(smem + OFF_WO + r * 24);
            float s = smem[OFF_WO + 72 + r];
            #pragma unroll
            for (int k = 0; k < 5; ++k) {
                float4 hv = hp[k], wv = wp[k];
                s += hv.x * wv.x + hv.y * wv.y + hv.z * wv.z + hv.w * wv.w;
            }
            out[((size_t)(ch * TC + tt) * BATCH + bbase + bb) * 3 + r] = s;
        }
    }
}

extern "C" void kernel_launch(void* const* d_in, const int* in_sizes, int n_in,
                              void* d_out, int out_size, void* d_ws, size_t ws_size,
                              hipStream_t stream) {
    const float* md    = (const float*)d_in[0];
    const float* W_emb = (const float*)d_in[1];
    const float* b_emb = (const float*)d_in[2];
    const float* W_ih  = (const float*)d_in[3];
    const float* b_ih  = (const float*)d_in[4];
    const float* W_hh  = (const float*)d_in[5];
    const float* b_hh  = (const float*)d_in[6];
    const float* W_out = (const float*)d_in[7];
    const float* b_out = (const float*)d_in[8];
    float* out = (float*)d_out;

    hipLaunchKernelGGL(lstm_tracker_kernel, dim3(BATCH / 2), dim3(64), 0, stream,
                       md, W_emb, b_emb, W_ih, b_ih, W_hh, b_hh, W_out, b_out, out);
}